// Round 16
// baseline (161.967 us; speedup 1.0000x reference)
//
#include <hip/hip_runtime.h>
#include <hip/hip_bf16.h>
#include <math.h>

#define EPS 1e-5f

typedef __attribute__((ext_vector_type(8))) __bf16 bf16x8;
typedef __attribute__((ext_vector_type(4))) float f32x4;

// ---------------- fused f32 -> bf16 conversion ----------------
struct CvtJobs {
    const float* src[12];
    __bf16* dst[12];
    int off[13];
};

__global__ __launch_bounds__(256) void cvt_k(CvtJobs J, int total) {
    int g = blockIdx.x * 256 + threadIdx.x;
    if (g >= total) return;
    int j = 0;
    #pragma unroll
    for (int t = 0; t < 11; ++t) j += (g >= J.off[t + 1]) ? 1 : 0;
    int lg = g - J.off[j];
    const float* s = J.src[j] + (size_t)lg * 8;
    float4 a = *(const float4*)s;
    float4 b = *(const float4*)(s + 4);
    bf16x8 o;
    o[0] = (__bf16)a.x; o[1] = (__bf16)a.y; o[2] = (__bf16)a.z; o[3] = (__bf16)a.w;
    o[4] = (__bf16)b.x; o[5] = (__bf16)b.y; o[6] = (__bf16)b.z; o[7] = (__bf16)b.w;
    *(bf16x8*)(J.dst[j] + (size_t)lg * 8) = o;
}

// ---------------- shared GEMM body (bf16 MFMA, T2 XOR-swizzled LDS) ----------------
// LDS tile [rows][64] bf16; 16B col-group XOR-swizzled by row&7 (conflict-free).
// global_load_lds writes linearly -> swizzle applied via permuted GLOBAL source
// col-group + identical XOR on the read side.
// Interleaved RoPE epilogue: out[2j]=x0*c-x1*s, out[2j+1]=x1*c+x0*s at original cols.
template<int BT, typename OutT, bool RELU, bool HAS_BIAS, bool ROPE>
__device__ __forceinline__ void gemm_body(const __bf16* __restrict__ A,
                                          const __bf16* __restrict__ W,
                                          const float* b0, const float* b1, const float* b2,
                                          int bshift,
                                          const float* disK,
                                          int ropeLo, int ropeHi, int dstride,
                                          OutT* __restrict__ C,
                                          int M, int N, int K,
                                          int bid, int nb, int gx,
                                          int kbeg, int kend) {
    constexpr int NI = BT / 32;
    __shared__ __bf16 As[BT * 64];
    __shared__ __bf16 Ws[BT * 64];

    const int tid  = threadIdx.x;
    const int wave = tid >> 6;
    const int lane = tid & 63;
    const int frow = lane & 15;
    const int fgrp = lane >> 4;

    const int v   = (bid & 7) * (nb >> 3) + (bid >> 3);
    const int bx  = (v % gx) * BT;
    const int by  = (v / gx) * BT;

    const int wr = (wave >> 1) * (BT / 2);
    const int wc = (wave & 1) * (BT / 2);
    const int ldr  = lane >> 3;
    const int ldcs = (((lane & 7) ^ ldr) & 7) * 8;   // swizzled global col-group

    f32x4 acc[NI][NI] = {};

    for (int k0 = kbeg; k0 < kend; k0 += 64) {
        #pragma unroll
        for (int it = 0; it < NI; ++it) {
            int chunk = it * 4 + wave;
            int r = chunk * 8 + ldr;
            const __bf16* ga = A + (size_t)(by + r) * K + k0 + ldcs;
            const __bf16* gw = W + (size_t)(bx + r) * K + k0 + ldcs;
            __builtin_amdgcn_global_load_lds(
                (const __attribute__((address_space(1))) unsigned int*)ga,
                (__attribute__((address_space(3))) unsigned int*)(As + chunk * 512),
                16, 0, 0);
            __builtin_amdgcn_global_load_lds(
                (const __attribute__((address_space(1))) unsigned int*)gw,
                (__attribute__((address_space(3))) unsigned int*)(Ws + chunk * 512),
                16, 0, 0);
        }
        __syncthreads();

        #pragma unroll
        for (int kk = 0; kk < 2; ++kk) {
            bf16x8 af[NI], wf[NI];
            #pragma unroll
            for (int i = 0; i < NI; ++i) {
                int row = wr + i * 16 + frow;
                int cg = (kk * 4 + fgrp) ^ (row & 7);
                af[i] = *(const bf16x8*)&As[row * 64 + cg * 8];
            }
            #pragma unroll
            for (int j = 0; j < NI; ++j) {
                int row = wc + j * 16 + frow;
                int cg = (kk * 4 + fgrp) ^ (row & 7);
                wf[j] = *(const bf16x8*)&Ws[row * 64 + cg * 8];
            }
            #pragma unroll
            for (int i = 0; i < NI; ++i)
                #pragma unroll
                for (int j = 0; j < NI; ++j)
                    acc[i][j] = __builtin_amdgcn_mfma_f32_16x16x32_bf16(af[i], wf[j], acc[i][j], 0, 0, 0);
        }
        __syncthreads();
    }

    #pragma unroll
    for (int i = 0; i < NI; ++i) {
        #pragma unroll
        for (int jj = 0; jj < 4; ++jj) {
            int row = by + wr + i * 16 + fgrp * 4 + jj;
            #pragma unroll
            for (int j = 0; j < NI; ++j) {
                int col = bx + wc + j * 16 + frow;
                float val = acc[i][j][jj];
                if (HAS_BIAS) {
                    int sel = col >> bshift;
                    const float* bp = sel == 0 ? b0 : (sel == 1 ? b1 : b2);
                    val += bp[col & (int)((1u << bshift) - 1)];
                }
                if (RELU) val = fmaxf(val, 0.0f);
                if (ROPE && col >= ropeLo && col < ropeHi) {
                    int hcol = col & 63;
                    int p = hcol >> 1;
                    int hbase = col - hcol;
                    const float* dr = disK + (size_t)row * dstride + (hbase - ropeLo);
                    float sv = dr[p], cv = dr[32 + p];
                    float pv = __shfl_xor(val, 1);
                    val = ((col & 1) == 0) ? (val * cv - pv * sv)
                                           : (val * cv + pv * sv);
                }
                C[(size_t)row * N + col] = (OutT)val;
            }
        }
    }
}

// ---------------- single-problem GEMM (split-K via blockIdx.z) ----------------
template<int BT, int KS, typename OutT, bool RELU, bool HAS_BIAS, bool ROPE>
__global__ __launch_bounds__(256) void gemm_bf16_k(const __bf16* __restrict__ A,
                                                   const __bf16* __restrict__ W,
                                                   const float* b0, const float* b1,
                                                   const float* b2, int bshift,
                                                   const float* disK,
                                                   int ropeLo, int ropeHi, int dstride,
                                                   OutT* __restrict__ C,
                                                   int M, int N, int K) {
    const int nb  = gridDim.x * gridDim.y;
    const int bid = blockIdx.y * gridDim.x + blockIdx.x;
    const int Kc  = K / KS;
    const int kbeg = blockIdx.z * Kc;
    OutT* Cz = C + (size_t)blockIdx.z * M * N;
    gemm_body<BT, OutT, RELU, HAS_BIAS, ROPE>(A, W, b0, b1, b2, bshift,
                                              disK, ropeLo, ropeHi, dstride,
                                              Cz, M, N, K, bid, nb, gridDim.x,
                                              kbeg, kbeg + Kc);
}

// ---------------- dual-problem GEMM (two independent problems, one dispatch) --------
struct GemmP {
    const __bf16* A;
    const __bf16* W;
    const float *b0, *b1, *b2;
    const float* disK;
    __bf16* C;
    int bshift, ropeLo, ropeHi, dstride;
    int M, N, K, gx, nb;
};

template<int BT>
__global__ __launch_bounds__(256) void gemm_dual_k(GemmP p0, GemmP p1, int nb0) {
    int bid = blockIdx.x;
    const GemmP& p = (bid < nb0) ? p0 : p1;
    int lb = (bid < nb0) ? bid : bid - nb0;
    gemm_body<BT, __bf16, false, true, true>(p.A, p.W, p.b0, p.b1, p.b2, p.bshift,
                                             p.disK, p.ropeLo, p.ropeHi, p.dstride,
                                             p.C, p.M, p.N, p.K, lb, p.nb, p.gx,
                                             0, p.K);
}

// ---------------- wo GEMM with fused key-split merge on the A operand ----------------
// Same XOR-swizzled LDS tiles as gemm_body.
template<int KS>
__global__ __launch_bounds__(256) void gemm_wo_k(const __bf16* __restrict__ Opart,
                                                 const float* __restrict__ lsums,
                                                 int prows, int H,
                                                 const __bf16* __restrict__ W,
                                                 float* __restrict__ C,
                                                 int M, int N, int K) {
    __shared__ __bf16 As[64 * 64];
    __shared__ __bf16 Ws[64 * 64];

    const int tid  = threadIdx.x;
    const int wave = tid >> 6;
    const int lane = tid & 63;
    const int frow = lane & 15;
    const int fgrp = lane >> 4;

    const int nb  = gridDim.x * gridDim.y;
    const int bid = blockIdx.y * gridDim.x + blockIdx.x;
    const int v   = (bid & 7) * (nb >> 3) + (bid >> 3);
    const int bx  = (v % gridDim.x) * 64;
    const int by  = (v / gridDim.x) * 64;

    const int Kc = K / KS;
    const int kbeg = blockIdx.z * Kc;
    float* Cz = C + (size_t)blockIdx.z * M * N;

    const int wr = (wave >> 1) * 32;
    const int wc = (wave & 1) * 32;
    const int ldr  = lane >> 3;
    const int ldcs = (((lane & 7) ^ ldr) & 7) * 8;

    f32x4 acc[2][2] = {};

    for (int k0 = kbeg; k0 < kbeg + Kc; k0 += 64) {
        const int h = k0 >> 6;
        #pragma unroll
        for (int it = 0; it < 2; ++it) {
            int chunk = it * 4 + wave;
            int r = chunk * 8 + ldr;
            size_t rid = (size_t)(by + r) * H + h;
            bf16x8 o0 = *(const bf16x8*)&Opart[rid * 64 + ldcs];
            bf16x8 o1 = *(const bf16x8*)&Opart[((size_t)prows + rid) * 64 + ldcs];
            float li = 1.0f / (lsums[rid] + lsums[prows + rid]);
            bf16x8 m;
            #pragma unroll
            for (int u = 0; u < 8; ++u)
                m[u] = (__bf16)(((float)o0[u] + (float)o1[u]) * li);
            *(bf16x8*)&As[chunk * 512 + lane * 8] = m;
            const __bf16* gw = W + (size_t)(bx + r) * K + k0 + ldcs;
            __builtin_amdgcn_global_load_lds(
                (const __attribute__((address_space(1))) unsigned int*)gw,
                (__attribute__((address_space(3))) unsigned int*)(Ws + chunk * 512),
                16, 0, 0);
        }
        __syncthreads();

        #pragma unroll
        for (int kk = 0; kk < 2; ++kk) {
            bf16x8 af[2], wf[2];
            #pragma unroll
            for (int i = 0; i < 2; ++i) {
                int row = wr + i * 16 + frow;
                int cg = (kk * 4 + fgrp) ^ (row & 7);
                af[i] = *(const bf16x8*)&As[row * 64 + cg * 8];
            }
            #pragma unroll
            for (int j = 0; j < 2; ++j) {
                int row = wc + j * 16 + frow;
                int cg = (kk * 4 + fgrp) ^ (row & 7);
                wf[j] = *(const bf16x8*)&Ws[row * 64 + cg * 8];
            }
            #pragma unroll
            for (int i = 0; i < 2; ++i)
                #pragma unroll
                for (int j = 0; j < 2; ++j)
                    acc[i][j] = __builtin_amdgcn_mfma_f32_16x16x32_bf16(af[i], wf[j], acc[i][j], 0, 0, 0);
        }
        __syncthreads();
    }

    #pragma unroll
    for (int i = 0; i < 2; ++i)
        #pragma unroll
        for (int jj = 0; jj < 4; ++jj) {
            int row = by + wr + i * 16 + fgrp * 4 + jj;
            #pragma unroll
            for (int j = 0; j < 2; ++j) {
                int col = bx + wc + j * 16 + frow;
                Cz[(size_t)row * N + col] = acc[i][j][jj];
            }
        }
}

// ---------------- MFMA flash attention: 64q/block, fixed-max softmax ----------------
// Q roped in-register with INTERLEAVED layout (matches GEMM-roped K).
template<bool CAUSAL, int NSPLIT>
__global__ __launch_bounds__(256) void attn_bf16_k(const __bf16* __restrict__ Q,
                                                   const __bf16* __restrict__ K,
                                                   const __bf16* __restrict__ V,
                                                   const float* __restrict__ disQ,
                                                   __bf16* __restrict__ Opart,
                                                   float* __restrict__ lsums,
                                                   int H, int LQ, int LM,
                                                   int qstride, int kvstride,
                                                   int prows) {
    __shared__ __bf16 Ks[64 * 72];
    __shared__ __bf16 Vt[64 * 72];
    __shared__ __bf16 Ps[4 * 16 * 72];

    const int nqt = LQ >> 6;
    const int nb  = gridDim.x;
    const int bid = blockIdx.x;
    const int v   = (bid & 7) * (nb >> 3) + (bid >> 3);
    int t = v;
    const int qt = t % nqt; t /= nqt;
    const int chunk = t % NSPLIT; t /= NSPLIT;
    const int h = t % H;
    const int b = t / H;
    const int q0 = qt * 64;

    const int tid  = threadIdx.x;
    const int wave = tid >> 6;
    const int lane = tid & 63;
    const int frow = lane & 15;
    const int fgrp = lane >> 4;

    // ---- Q fragments, fused INTERLEAVED RoPE ----
    const int qrow = q0 + wave * 16 + frow;
    bf16x8 qf0, qf1;
    {
        const __bf16* qp = Q + ((size_t)b * LQ + qrow) * qstride + h * 64 + fgrp * 8;
        bf16x8 xa = *(const bf16x8*)qp;
        bf16x8 xb = *(const bf16x8*)(qp + 32);
        const float* dq = disQ + (((size_t)b * LQ + qrow) * H + h) * 64;
        #pragma unroll
        for (int u = 0; u < 4; ++u) {
            float sv = dq[fgrp * 4 + u], cv = dq[32 + fgrp * 4 + u];
            float x0 = (float)xa[2 * u], x1 = (float)xa[2 * u + 1];
            qf0[2 * u]     = (__bf16)(x0 * cv - x1 * sv);
            qf0[2 * u + 1] = (__bf16)(x1 * cv + x0 * sv);
            sv = dq[16 + fgrp * 4 + u]; cv = dq[48 + fgrp * 4 + u];
            x0 = (float)xb[2 * u]; x1 = (float)xb[2 * u + 1];
            qf1[2 * u]     = (__bf16)(x0 * cv - x1 * sv);
            qf1[2 * u + 1] = (__bf16)(x1 * cv + x0 * sv);
        }
    }

    f32x4 oacc[4] = {};
    float lsum[4] = {};

    const int kbAll = CAUSAL ? (qt + 1) : (LM >> 6);
    const int kcnt  = (LM >> 6) / NSPLIT;
    const int kb0   = chunk * kcnt;
    const int kb1   = min(kbAll, kb0 + kcnt);

    const int r   = tid >> 2;
    const int c0q = tid & 3;
    const int kphys = (r & 7) + 8 * ((r >> 3) ^ (2 * c0q));

    for (int kb = kb0; kb < kb1; ++kb) {
        const int m0 = kb * 64;
        {
            const __bf16* kp = K + ((size_t)b * LM + m0 + r) * kvstride + h * 64 + c0q * 16;
            *(bf16x8*)&Ks[r * 72 + c0q * 16]     = *(const bf16x8*)kp;
            *(bf16x8*)&Ks[r * 72 + c0q * 16 + 8] = *(const bf16x8*)(kp + 8);
        }
        {
            const __bf16* vp = V + ((size_t)b * LM + m0 + r) * kvstride + h * 64 + c0q * 16;
            bf16x8 va = *(const bf16x8*)vp;
            bf16x8 vb = *(const bf16x8*)(vp + 8);
            #pragma unroll
            for (int j = 0; j < 8; ++j) {
                Vt[(c0q * 16 + j) * 72 + kphys]     = va[j];
                Vt[(c0q * 16 + 8 + j) * 72 + kphys] = vb[j];
            }
        }
        __syncthreads();

        f32x4 s[4];
        #pragma unroll
        for (int n = 0; n < 4; ++n) {
            bf16x8 kf0 = *(const bf16x8*)&Ks[(n * 16 + frow) * 72 + fgrp * 8];
            bf16x8 kf1 = *(const bf16x8*)&Ks[(n * 16 + frow) * 72 + 32 + fgrp * 8];
            f32x4 tt = {0.f, 0.f, 0.f, 0.f};
            tt = __builtin_amdgcn_mfma_f32_16x16x32_bf16(qf0, kf0, tt, 0, 0, 0);
            tt = __builtin_amdgcn_mfma_f32_16x16x32_bf16(qf1, kf1, tt, 0, 0, 0);
            s[n] = tt;
        }

        #pragma unroll
        for (int n = 0; n < 4; ++n)
            #pragma unroll
            for (int jj = 0; jj < 4; ++jj) {
                bool valid = (!CAUSAL) ||
                    ((m0 + n * 16 + frow) <= (q0 + wave * 16 + fgrp * 4 + jj));
                s[n][jj] = valid ? __expf(s[n][jj] * 0.125f - 8.0f) : 0.0f;
            }

        #pragma unroll
        for (int jj = 0; jj < 4; ++jj) {
            float rs = (s[0][jj] + s[1][jj]) + (s[2][jj] + s[3][jj]);
            #pragma unroll
            for (int msk = 8; msk >= 1; msk >>= 1) rs += __shfl_xor(rs, msk);
            lsum[jj] += rs;
        }

        #pragma unroll
        for (int n = 0; n < 4; ++n)
            #pragma unroll
            for (int jj = 0; jj < 4; ++jj) {
                int q = fgrp * 4 + jj;
                int kidx = (frow & 7) + 8 * (((2 * n) + (frow >> 3)) ^ (2 * ((q >> 3) & 1)));
                Ps[wave * 1152 + q * 72 + kidx] = (__bf16)s[n][jj];
            }

        #pragma unroll
        for (int c = 0; c < 2; ++c) {
            int pblk = (c * 4 + fgrp) ^ (2 * ((frow >> 3) & 1));
            bf16x8 pf = *(const bf16x8*)&Ps[wave * 1152 + frow * 72 + 8 * pblk];
            #pragma unroll
            for (int n = 0; n < 4; ++n) {
                int vblk = (c * 4 + fgrp) ^ (2 * n);
                bf16x8 vf = *(const bf16x8*)&Vt[(n * 16 + frow) * 72 + 8 * vblk];
                oacc[n] = __builtin_amdgcn_mfma_f32_16x16x32_bf16(pf, vf, oacc[n], 0, 0, 0);
            }
        }
        __syncthreads();
    }

    #pragma unroll
    for (int jj = 0; jj < 4; ++jj) {
        int q = q0 + wave * 16 + fgrp * 4 + jj;
        size_t ridx = (size_t)chunk * prows + ((size_t)b * LQ + q) * H + h;
        if (frow == 0) lsums[ridx] = lsum[jj];
        #pragma unroll
        for (int n = 0; n < 4; ++n)
            Opart[ridx * 64 + n * 16 + frow] = (__bf16)oacc[n][jj];
    }
}

// ---------------- deep_norm with NP partial-sum inputs + optional bias / A-copy ------
template<int NP, bool HASB, bool WRITE_BF>
__global__ __launch_bounds__(256) void deepnorm_k(const float* __restrict__ x,
                                                  const float* __restrict__ p0,
                                                  const float* __restrict__ p1,
                                                  const float* __restrict__ p2,
                                                  const float* __restrict__ p3,
                                                  const float* __restrict__ bias,
                                                  const float* __restrict__ g,
                                                  const float* __restrict__ b,
                                                  float* __restrict__ out,
                                                  __bf16* __restrict__ out_bf,
                                                  const float* __restrict__ Ain,
                                                  float* __restrict__ Aout) {
    int row = blockIdx.x;
    int tid = threadIdx.x;
    if (Aout && row == 0 && tid == 0) Aout[0] = Ain[0];
    size_t i0 = (size_t)row * 512 + tid, i1 = i0 + 256;
    float a0 = p0[i0], a1 = p0[i1];
    if (NP > 1) { a0 += p1[i0]; a1 += p1[i1]; }
    if (NP > 2) { a0 += p2[i0]; a1 += p2[i1]; }
    if (NP > 3) { a0 += p3[i0]; a1 += p3[i1]; }
    if (HASB)   { a0 += bias[tid]; a1 += bias[tid + 256]; }
    float v0 = x[i0] * 2.0f + a0;
    float v1 = x[i1] * 2.0f + a1;

    __shared__ float red[4];
    int wave = tid >> 6, lane = tid & 63;

    float s = v0 + v1;
    #pragma unroll
    for (int o = 32; o >= 1; o >>= 1) s += __shfl_xor(s, o);
    if (lane == 0) red[wave] = s;
    __syncthreads();
    float mean = (red[0] + red[1] + red[2] + red[3]) * (1.0f / 512.0f);

    float d0 = v0 - mean, d1 = v1 - mean;
    float vs = d0 * d0 + d1 * d1;
    #pragma unroll
    for (int o = 32; o >= 1; o >>= 1) vs += __shfl_xor(vs, o);
    __syncthreads();
    if (lane == 0) red[wave] = vs;
    __syncthreads();
    float var = (red[0] + red[1] + red[2] + red[3]) * (1.0f / 512.0f);
    float inv = rsqrtf(var + EPS);

    float o0 = d0 * inv * g[tid] + b[tid];
    float o1 = d1 * inv * g[tid + 256] + b[tid + 256];
    out[i0] = o0;
    out[i1] = o1;
    if (WRITE_BF) {
        out_bf[i0] = (__bf16)o0;
        out_bf[i1] = (__bf16)o1;
    }
}

// ---------------- launch ----------------
extern "C" void kernel_launch(void* const* d_in, const int* in_sizes, int n_in,
                              void* d_out, int out_size, void* d_ws, size_t ws_size,
                              hipStream_t stream) {
    const float* tgt  = (const float*)d_in[0];
    const float* mem  = (const float*)d_in[1];
    const float* dis_k1 = (const float*)d_in[2];
    const float* dis_q1 = (const float*)d_in[3];
    const float* dis_q2 = (const float*)d_in[4];
    const float* dis_k2 = (const float*)d_in[5];
    const float* A_in   = (const float*)d_in[10];
    const float* wq1 = (const float*)d_in[11]; const float* bq1 = (const float*)d_in[12];
    const float* wk1 = (const float*)d_in[13]; const float* bk1 = (const float*)d_in[14];
    const float* wv1 = (const float*)d_in[15]; const float* bv1 = (const float*)d_in[16];
    const float* wo1 = (const float*)d_in[17]; const float* bo1 = (const float*)d_in[18];
    const float* ln1g = (const float*)d_in[19]; const float* ln1b = (const float*)d_in[20];
    const float* wq2 = (const float*)d_in[21]; const float* bq2 = (const float*)d_in[22];
    const float* wk2 = (const float*)d_in[23]; const float* bk2 = (const float*)d_in[24];
    const float* wv2 = (const float*)d_in[25]; const float* bv2 = (const float*)d_in[26];
    const float* wo2 = (const float*)d_in[27]; const float* bo2 = (const float*)d_in[28];
    const float* ln2g = (const float*)d_in[29]; const float* ln2b = (const float*)d_in[30];
    const float* wff1 = (const float*)d_in[31]; const float* wff2 = (const float*)d_in[32];
    const float* ln3g = (const float*)d_in[33]; const float* ln3b = (const float*)d_in[34];

    char* ws = (char*)d_ws;
    auto MB = [&](size_t mb) { return ws + mb * 1024 * 1024; };

    __bf16* wqkv1_bf = (__bf16*)MB(0);     // 1.5MB
    __bf16* wo1_bf   = (__bf16*)MB(2);     // 0.5MB
    __bf16* wq2_bf   = (__bf16*)MB(3);     // 1MB
    __bf16* wkv2_bf  = (__bf16*)MB(4);     // 2MB
    __bf16* wo2_bf   = (__bf16*)MB(6);     // 1MB
    __bf16* wff1_bf  = (__bf16*)MB(7);     // 2MB
    __bf16* wff2_bf  = (__bf16*)MB(9);     // 2MB
    __bf16* tgt_bf   = (__bf16*)MB(11);    // 2MB, reused as x1_bf after qkv1+kv2
    __bf16* mem_bf   = (__bf16*)MB(13);    // 4MB
    __bf16* qkv1_bf  = (__bf16*)MB(17);    // 6MB, reused as q2_bf after attn1
    __bf16* Opart    = (__bf16*)MB(23);    // 8MB (23..31); reused as ffh_bf (8MB)
    float*  x1       = (float*)MB(31);     // 4MB (31..35)
    float*  post0    = (float*)MB(35);     // 4MB (35..39)
    float*  post1    = (float*)MB(39);     // 4MB (39..43)
    __bf16* kv2_bf   = (__bf16*)MB(43);    // 16MB (43..59) -- own region (written early)
    float*  x2       = (float*)MB(59);     // 4MB (59..63)
    __bf16* x2_bf    = (__bf16*)MB(63);    // 2MB (63..65)
    float*  lsums    = (float*)MB(65);     // 0.25MB
    __bf16* x1_bf    = tgt_bf;
    __bf16* q2_bf    = qkv1_bf;
    __bf16* ffh_bf   = Opart;

    float* out = (float*)d_out;

    // ---- conversions ----
    CvtJobs J;
    const float* srcs[12] = {tgt, mem, wq1, wk1, wv1, wo1, wq2, wk2, wv2, wo2, wff1, wff2};
    __bf16* dsts[12] = {tgt_bf, mem_bf, wqkv1_bf, wqkv1_bf + 262144, wqkv1_bf + 524288,
                        wo1_bf, wq2_bf, wkv2_bf, wkv2_bf + 524288, wo2_bf, wff1_bf, wff2_bf};
    int sizes[12] = {2048 * 512, 4096 * 512, 512 * 512, 512 * 512, 512 * 512, 512 * 512,
                     1024 * 512, 1024 * 512, 1024 * 512, 1024 * 512, 2048 * 512, 512 * 2048};
    int acc = 0;
    for (int i = 0; i < 12; ++i) { J.src[i] = srcs[i]; J.dst[i] = dsts[i]; J.off[i] = acc; acc += sizes[i] / 8; }
    J.off[12] = acc;
    cvt_k<<<(acc + 255) / 256, 256, 0, stream>>>(J, acc);

    // ---- merged qkv1 + kv2, 128x128 tiles (both depend only on cvt) ----
    GemmP p0, p1;
    p0.A = tgt_bf;  p0.W = wqkv1_bf; p0.b0 = bq1; p0.b1 = bk1; p0.b2 = bv1;
    p0.disK = dis_k1; p0.C = qkv1_bf;
    p0.bshift = 9; p0.ropeLo = 512; p0.ropeHi = 1024; p0.dstride = 512;
    p0.M = 2048; p0.N = 1536; p0.K = 512; p0.gx = 12; p0.nb = 192;
    p1.A = mem_bf;  p1.W = wkv2_bf;  p1.b0 = bk2; p1.b1 = bv2; p1.b2 = bv2;
    p1.disK = dis_k2; p1.C = kv2_bf;
    p1.bshift = 10; p1.ropeLo = 0; p1.ropeHi = 1024; p1.dstride = 1024;
    p1.M = 4096; p1.N = 2048; p1.K = 512; p1.gx = 16; p1.nb = 512;
    gemm_dual_k<128><<<192 + 512, 256, 0, stream>>>(p0, p1, 192);

    // ---- Phase 1: self-attention ----
    attn_bf16_k<true, 2><<<512, 256, 0, stream>>>(qkv1_bf, qkv1_bf + 512, qkv1_bf + 1024,
                                                  dis_q1, Opart, lsums,
                                                  8, 512, 512, 1536, 1536, 16384);
    gemm_wo_k<2><<<dim3(8, 32, 2), 256, 0, stream>>>(Opart, lsums, 16384, 8,
                                                     wo1_bf, post0, 2048, 512, 512);
    deepnorm_k<2, true, true><<<2048, 256, 0, stream>>>(tgt, post0, post1, nullptr, nullptr,
                                                        bo1, ln1g, ln1b, x1, x1_bf,
                                                        nullptr, nullptr);

    // ---- Phase 2: cross-attention ----
    gemm_bf16_k<64, 1, __bf16, false, true, false><<<dim3(16, 32), 256, 0, stream>>>(
        x1_bf, wq2_bf, bq2, bq2, bq2, 31, nullptr, 0, 0, 0,
        q2_bf, 2048, 1024, 512);
    attn_bf16_k<false, 2><<<1024, 256, 0, stream>>>(q2_bf, kv2_bf, kv2_bf + 1024,
                                                    dis_q2, Opart, lsums,
                                                    16, 512, 1024, 1024, 2048, 32768);
    gemm_wo_k<2><<<dim3(8, 32, 2), 256, 0, stream>>>(Opart, lsums, 32768, 16,
                                                     wo2_bf, post0, 2048, 512, 1024);
    deepnorm_k<2, true, true><<<2048, 256, 0, stream>>>(x1, post0, post1, nullptr, nullptr,
                                                        bo2, ln2g, ln2b, x2, x2_bf,
                                                        nullptr, nullptr);

    // ---- Phase 3: FFN ----
    gemm_bf16_k<128, 1, __bf16, true, false, false><<<dim3(16, 16), 256, 0, stream>>>(
        x2_bf, wff1_bf, nullptr, nullptr, nullptr, 31, nullptr, 0, 0, 0,
        ffh_bf, 2048, 2048, 512);
    gemm_bf16_k<64, 2, float, false, false, false><<<dim3(8, 32, 2), 256, 0, stream>>>(
        ffh_bf, wff2_bf, nullptr, nullptr, nullptr, 31, nullptr, 0, 0, 0,
        post0, 2048, 512, 2048);
    deepnorm_k<2, false, false><<<2048, 256, 0, stream>>>(x2, post0, post1, nullptr, nullptr,
                                                          nullptr, ln3g, ln3b, out, nullptr,
                                                          A_in, out + 2048 * 512);
}

// Round 17
// 152.785 us; speedup vs baseline: 1.0601x; 1.0601x over previous
//
#include <hip/hip_runtime.h>
#include <hip/hip_bf16.h>
#include <math.h>

#define EPS 1e-5f

typedef __attribute__((ext_vector_type(8))) __bf16 bf16x8;
typedef __attribute__((ext_vector_type(4))) float f32x4;

// ---------------- fused f32 -> bf16 conversion ----------------
struct CvtJobs {
    const float* src[12];
    __bf16* dst[12];
    int off[13];
};

__global__ __launch_bounds__(256) void cvt_k(CvtJobs J, int total) {
    int g = blockIdx.x * 256 + threadIdx.x;
    if (g >= total) return;
    int j = 0;
    #pragma unroll
    for (int t = 0; t < 11; ++t) j += (g >= J.off[t + 1]) ? 1 : 0;
    int lg = g - J.off[j];
    const float* s = J.src[j] + (size_t)lg * 8;
    float4 a = *(const float4*)s;
    float4 b = *(const float4*)(s + 4);
    bf16x8 o;
    o[0] = (__bf16)a.x; o[1] = (__bf16)a.y; o[2] = (__bf16)a.z; o[3] = (__bf16)a.w;
    o[4] = (__bf16)b.x; o[5] = (__bf16)b.y; o[6] = (__bf16)b.z; o[7] = (__bf16)b.w;
    *(bf16x8*)(J.dst[j] + (size_t)lg * 8) = o;
}

// ---------------- shared GEMM body (bf16 MFMA, T2 XOR-swizzled LDS) ----------------
// LDS tile [rows][64] bf16; 16B col-group XOR-swizzled by row&7 (conflict-free).
// global_load_lds writes linearly -> swizzle applied via permuted GLOBAL source
// col-group + identical XOR on the read side.
// Interleaved RoPE epilogue: out[2j]=x0*c-x1*s, out[2j+1]=x1*c+x0*s at original cols.
// NOTE: 64x64 tile is the measured optimum at these problem sizes (R15: occupancy 45%,
// 2816 blocks). 128x128 regressed (R16: 704 blocks, occupancy 15%) -- tile choice is
// grid-size-dependent.
template<int BT, typename OutT, bool RELU, bool HAS_BIAS, bool ROPE>
__device__ __forceinline__ void gemm_body(const __bf16* __restrict__ A,
                                          const __bf16* __restrict__ W,
                                          const float* b0, const float* b1, const float* b2,
                                          int bshift,
                                          const float* disK,
                                          int ropeLo, int ropeHi, int dstride,
                                          OutT* __restrict__ C,
                                          int M, int N, int K,
                                          int bid, int nb, int gx,
                                          int kbeg, int kend) {
    constexpr int NI = BT / 32;
    __shared__ __bf16 As[BT * 64];
    __shared__ __bf16 Ws[BT * 64];

    const int tid  = threadIdx.x;
    const int wave = tid >> 6;
    const int lane = tid & 63;
    const int frow = lane & 15;
    const int fgrp = lane >> 4;

    const int v   = (bid & 7) * (nb >> 3) + (bid >> 3);
    const int bx  = (v % gx) * BT;
    const int by  = (v / gx) * BT;

    const int wr = (wave >> 1) * (BT / 2);
    const int wc = (wave & 1) * (BT / 2);
    const int ldr  = lane >> 3;
    const int ldcs = (((lane & 7) ^ ldr) & 7) * 8;   // swizzled global col-group

    f32x4 acc[NI][NI] = {};

    for (int k0 = kbeg; k0 < kend; k0 += 64) {
        #pragma unroll
        for (int it = 0; it < NI; ++it) {
            int chunk = it * 4 + wave;
            int r = chunk * 8 + ldr;
            const __bf16* ga = A + (size_t)(by + r) * K + k0 + ldcs;
            const __bf16* gw = W + (size_t)(bx + r) * K + k0 + ldcs;
            __builtin_amdgcn_global_load_lds(
                (const __attribute__((address_space(1))) unsigned int*)ga,
                (__attribute__((address_space(3))) unsigned int*)(As + chunk * 512),
                16, 0, 0);
            __builtin_amdgcn_global_load_lds(
                (const __attribute__((address_space(1))) unsigned int*)gw,
                (__attribute__((address_space(3))) unsigned int*)(Ws + chunk * 512),
                16, 0, 0);
        }
        __syncthreads();

        #pragma unroll
        for (int kk = 0; kk < 2; ++kk) {
            bf16x8 af[NI], wf[NI];
            #pragma unroll
            for (int i = 0; i < NI; ++i) {
                int row = wr + i * 16 + frow;
                int cg = (kk * 4 + fgrp) ^ (row & 7);
                af[i] = *(const bf16x8*)&As[row * 64 + cg * 8];
            }
            #pragma unroll
            for (int j = 0; j < NI; ++j) {
                int row = wc + j * 16 + frow;
                int cg = (kk * 4 + fgrp) ^ (row & 7);
                wf[j] = *(const bf16x8*)&Ws[row * 64 + cg * 8];
            }
            #pragma unroll
            for (int i = 0; i < NI; ++i)
                #pragma unroll
                for (int j = 0; j < NI; ++j)
                    acc[i][j] = __builtin_amdgcn_mfma_f32_16x16x32_bf16(af[i], wf[j], acc[i][j], 0, 0, 0);
        }
        __syncthreads();
    }

    #pragma unroll
    for (int i = 0; i < NI; ++i) {
        #pragma unroll
        for (int jj = 0; jj < 4; ++jj) {
            int row = by + wr + i * 16 + fgrp * 4 + jj;
            #pragma unroll
            for (int j = 0; j < NI; ++j) {
                int col = bx + wc + j * 16 + frow;
                float val = acc[i][j][jj];
                if (HAS_BIAS) {
                    int sel = col >> bshift;
                    const float* bp = sel == 0 ? b0 : (sel == 1 ? b1 : b2);
                    val += bp[col & (int)((1u << bshift) - 1)];
                }
                if (RELU) val = fmaxf(val, 0.0f);
                if (ROPE && col >= ropeLo && col < ropeHi) {
                    int hcol = col & 63;
                    int p = hcol >> 1;
                    int hbase = col - hcol;
                    const float* dr = disK + (size_t)row * dstride + (hbase - ropeLo);
                    float sv = dr[p], cv = dr[32 + p];
                    float pv = __shfl_xor(val, 1);
                    val = ((col & 1) == 0) ? (val * cv - pv * sv)
                                           : (val * cv + pv * sv);
                }
                C[(size_t)row * N + col] = (OutT)val;
            }
        }
    }
}

// ---------------- single-problem GEMM (split-K via blockIdx.z) ----------------
template<int BT, int KS, typename OutT, bool RELU, bool HAS_BIAS, bool ROPE>
__global__ __launch_bounds__(256) void gemm_bf16_k(const __bf16* __restrict__ A,
                                                   const __bf16* __restrict__ W,
                                                   const float* b0, const float* b1,
                                                   const float* b2, int bshift,
                                                   const float* disK,
                                                   int ropeLo, int ropeHi, int dstride,
                                                   OutT* __restrict__ C,
                                                   int M, int N, int K) {
    const int nb  = gridDim.x * gridDim.y;
    const int bid = blockIdx.y * gridDim.x + blockIdx.x;
    const int Kc  = K / KS;
    const int kbeg = blockIdx.z * Kc;
    OutT* Cz = C + (size_t)blockIdx.z * M * N;
    gemm_body<BT, OutT, RELU, HAS_BIAS, ROPE>(A, W, b0, b1, b2, bshift,
                                              disK, ropeLo, ropeHi, dstride,
                                              Cz, M, N, K, bid, nb, gridDim.x,
                                              kbeg, kbeg + Kc);
}

// ---------------- dual-problem GEMM (two independent problems, one dispatch) --------
struct GemmP {
    const __bf16* A;
    const __bf16* W;
    const float *b0, *b1, *b2;
    const float* disK;
    __bf16* C;
    int bshift, ropeLo, ropeHi, dstride;
    int M, N, K, gx, nb;
};

template<int BT>
__global__ __launch_bounds__(256) void gemm_dual_k(GemmP p0, GemmP p1, int nb0) {
    int bid = blockIdx.x;
    const GemmP& p = (bid < nb0) ? p0 : p1;
    int lb = (bid < nb0) ? bid : bid - nb0;
    gemm_body<BT, __bf16, false, true, true>(p.A, p.W, p.b0, p.b1, p.b2, p.bshift,
                                             p.disK, p.ropeLo, p.ropeHi, p.dstride,
                                             p.C, p.M, p.N, p.K, lb, p.nb, p.gx,
                                             0, p.K);
}

// ---------------- wo GEMM with fused key-split merge on the A operand ----------------
// Same XOR-swizzled LDS tiles as gemm_body.
template<int KS>
__global__ __launch_bounds__(256) void gemm_wo_k(const __bf16* __restrict__ Opart,
                                                 const float* __restrict__ lsums,
                                                 int prows, int H,
                                                 const __bf16* __restrict__ W,
                                                 float* __restrict__ C,
                                                 int M, int N, int K) {
    __shared__ __bf16 As[64 * 64];
    __shared__ __bf16 Ws[64 * 64];

    const int tid  = threadIdx.x;
    const int wave = tid >> 6;
    const int lane = tid & 63;
    const int frow = lane & 15;
    const int fgrp = lane >> 4;

    const int nb  = gridDim.x * gridDim.y;
    const int bid = blockIdx.y * gridDim.x + blockIdx.x;
    const int v   = (bid & 7) * (nb >> 3) + (bid >> 3);
    const int bx  = (v % gridDim.x) * 64;
    const int by  = (v / gridDim.x) * 64;

    const int Kc = K / KS;
    const int kbeg = blockIdx.z * Kc;
    float* Cz = C + (size_t)blockIdx.z * M * N;

    const int wr = (wave >> 1) * 32;
    const int wc = (wave & 1) * 32;
    const int ldr  = lane >> 3;
    const int ldcs = (((lane & 7) ^ ldr) & 7) * 8;

    f32x4 acc[2][2] = {};

    for (int k0 = kbeg; k0 < kbeg + Kc; k0 += 64) {
        const int h = k0 >> 6;
        #pragma unroll
        for (int it = 0; it < 2; ++it) {
            int chunk = it * 4 + wave;
            int r = chunk * 8 + ldr;
            size_t rid = (size_t)(by + r) * H + h;
            bf16x8 o0 = *(const bf16x8*)&Opart[rid * 64 + ldcs];
            bf16x8 o1 = *(const bf16x8*)&Opart[((size_t)prows + rid) * 64 + ldcs];
            float li = 1.0f / (lsums[rid] + lsums[prows + rid]);
            bf16x8 m;
            #pragma unroll
            for (int u = 0; u < 8; ++u)
                m[u] = (__bf16)(((float)o0[u] + (float)o1[u]) * li);
            *(bf16x8*)&As[chunk * 512 + lane * 8] = m;
            const __bf16* gw = W + (size_t)(bx + r) * K + k0 + ldcs;
            __builtin_amdgcn_global_load_lds(
                (const __attribute__((address_space(1))) unsigned int*)gw,
                (__attribute__((address_space(3))) unsigned int*)(Ws + chunk * 512),
                16, 0, 0);
        }
        __syncthreads();

        #pragma unroll
        for (int kk = 0; kk < 2; ++kk) {
            bf16x8 af[2], wf[2];
            #pragma unroll
            for (int i = 0; i < 2; ++i) {
                int row = wr + i * 16 + frow;
                int cg = (kk * 4 + fgrp) ^ (row & 7);
                af[i] = *(const bf16x8*)&As[row * 64 + cg * 8];
            }
            #pragma unroll
            for (int j = 0; j < 2; ++j) {
                int row = wc + j * 16 + frow;
                int cg = (kk * 4 + fgrp) ^ (row & 7);
                wf[j] = *(const bf16x8*)&Ws[row * 64 + cg * 8];
            }
            #pragma unroll
            for (int i = 0; i < 2; ++i)
                #pragma unroll
                for (int j = 0; j < 2; ++j)
                    acc[i][j] = __builtin_amdgcn_mfma_f32_16x16x32_bf16(af[i], wf[j], acc[i][j], 0, 0, 0);
        }
        __syncthreads();
    }

    #pragma unroll
    for (int i = 0; i < 2; ++i)
        #pragma unroll
        for (int jj = 0; jj < 4; ++jj) {
            int row = by + wr + i * 16 + fgrp * 4 + jj;
            #pragma unroll
            for (int j = 0; j < 2; ++j) {
                int col = bx + wc + j * 16 + frow;
                Cz[(size_t)row * N + col] = acc[i][j][jj];
            }
        }
}

// ---------------- MFMA flash attention: 64q/block, fixed-max softmax ----------------
// Q roped in-register with INTERLEAVED layout (matches GEMM-roped K).
template<bool CAUSAL, int NSPLIT>
__global__ __launch_bounds__(256) void attn_bf16_k(const __bf16* __restrict__ Q,
                                                   const __bf16* __restrict__ K,
                                                   const __bf16* __restrict__ V,
                                                   const float* __restrict__ disQ,
                                                   __bf16* __restrict__ Opart,
                                                   float* __restrict__ lsums,
                                                   int H, int LQ, int LM,
                                                   int qstride, int kvstride,
                                                   int prows) {
    __shared__ __bf16 Ks[64 * 72];
    __shared__ __bf16 Vt[64 * 72];
    __shared__ __bf16 Ps[4 * 16 * 72];

    const int nqt = LQ >> 6;
    const int nb  = gridDim.x;
    const int bid = blockIdx.x;
    const int v   = (bid & 7) * (nb >> 3) + (bid >> 3);
    int t = v;
    const int qt = t % nqt; t /= nqt;
    const int chunk = t % NSPLIT; t /= NSPLIT;
    const int h = t % H;
    const int b = t / H;
    const int q0 = qt * 64;

    const int tid  = threadIdx.x;
    const int wave = tid >> 6;
    const int lane = tid & 63;
    const int frow = lane & 15;
    const int fgrp = lane >> 4;

    // ---- Q fragments, fused INTERLEAVED RoPE ----
    const int qrow = q0 + wave * 16 + frow;
    bf16x8 qf0, qf1;
    {
        const __bf16* qp = Q + ((size_t)b * LQ + qrow) * qstride + h * 64 + fgrp * 8;
        bf16x8 xa = *(const bf16x8*)qp;
        bf16x8 xb = *(const bf16x8*)(qp + 32);
        const float* dq = disQ + (((size_t)b * LQ + qrow) * H + h) * 64;
        #pragma unroll
        for (int u = 0; u < 4; ++u) {
            float sv = dq[fgrp * 4 + u], cv = dq[32 + fgrp * 4 + u];
            float x0 = (float)xa[2 * u], x1 = (float)xa[2 * u + 1];
            qf0[2 * u]     = (__bf16)(x0 * cv - x1 * sv);
            qf0[2 * u + 1] = (__bf16)(x1 * cv + x0 * sv);
            sv = dq[16 + fgrp * 4 + u]; cv = dq[48 + fgrp * 4 + u];
            x0 = (float)xb[2 * u]; x1 = (float)xb[2 * u + 1];
            qf1[2 * u]     = (__bf16)(x0 * cv - x1 * sv);
            qf1[2 * u + 1] = (__bf16)(x1 * cv + x0 * sv);
        }
    }

    f32x4 oacc[4] = {};
    float lsum[4] = {};

    const int kbAll = CAUSAL ? (qt + 1) : (LM >> 6);
    const int kcnt  = (LM >> 6) / NSPLIT;
    const int kb0   = chunk * kcnt;
    const int kb1   = min(kbAll, kb0 + kcnt);

    const int r   = tid >> 2;
    const int c0q = tid & 3;
    const int kphys = (r & 7) + 8 * ((r >> 3) ^ (2 * c0q));

    for (int kb = kb0; kb < kb1; ++kb) {
        const int m0 = kb * 64;
        {
            const __bf16* kp = K + ((size_t)b * LM + m0 + r) * kvstride + h * 64 + c0q * 16;
            *(bf16x8*)&Ks[r * 72 + c0q * 16]     = *(const bf16x8*)kp;
            *(bf16x8*)&Ks[r * 72 + c0q * 16 + 8] = *(const bf16x8*)(kp + 8);
        }
        {
            const __bf16* vp = V + ((size_t)b * LM + m0 + r) * kvstride + h * 64 + c0q * 16;
            bf16x8 va = *(const bf16x8*)vp;
            bf16x8 vb = *(const bf16x8*)(vp + 8);
            #pragma unroll
            for (int j = 0; j < 8; ++j) {
                Vt[(c0q * 16 + j) * 72 + kphys]     = va[j];
                Vt[(c0q * 16 + 8 + j) * 72 + kphys] = vb[j];
            }
        }
        __syncthreads();

        f32x4 s[4];
        #pragma unroll
        for (int n = 0; n < 4; ++n) {
            bf16x8 kf0 = *(const bf16x8*)&Ks[(n * 16 + frow) * 72 + fgrp * 8];
            bf16x8 kf1 = *(const bf16x8*)&Ks[(n * 16 + frow) * 72 + 32 + fgrp * 8];
            f32x4 tt = {0.f, 0.f, 0.f, 0.f};
            tt = __builtin_amdgcn_mfma_f32_16x16x32_bf16(qf0, kf0, tt, 0, 0, 0);
            tt = __builtin_amdgcn_mfma_f32_16x16x32_bf16(qf1, kf1, tt, 0, 0, 0);
            s[n] = tt;
        }

        #pragma unroll
        for (int n = 0; n < 4; ++n)
            #pragma unroll
            for (int jj = 0; jj < 4; ++jj) {
                bool valid = (!CAUSAL) ||
                    ((m0 + n * 16 + frow) <= (q0 + wave * 16 + fgrp * 4 + jj));
                s[n][jj] = valid ? __expf(s[n][jj] * 0.125f - 8.0f) : 0.0f;
            }

        #pragma unroll
        for (int jj = 0; jj < 4; ++jj) {
            float rs = (s[0][jj] + s[1][jj]) + (s[2][jj] + s[3][jj]);
            #pragma unroll
            for (int msk = 8; msk >= 1; msk >>= 1) rs += __shfl_xor(rs, msk);
            lsum[jj] += rs;
        }

        #pragma unroll
        for (int n = 0; n < 4; ++n)
            #pragma unroll
            for (int jj = 0; jj < 4; ++jj) {
                int q = fgrp * 4 + jj;
                int kidx = (frow & 7) + 8 * (((2 * n) + (frow >> 3)) ^ (2 * ((q >> 3) & 1)));
                Ps[wave * 1152 + q * 72 + kidx] = (__bf16)s[n][jj];
            }

        #pragma unroll
        for (int c = 0; c < 2; ++c) {
            int pblk = (c * 4 + fgrp) ^ (2 * ((frow >> 3) & 1));
            bf16x8 pf = *(const bf16x8*)&Ps[wave * 1152 + frow * 72 + 8 * pblk];
            #pragma unroll
            for (int n = 0; n < 4; ++n) {
                int vblk = (c * 4 + fgrp) ^ (2 * n);
                bf16x8 vf = *(const bf16x8*)&Vt[(n * 16 + frow) * 72 + 8 * vblk];
                oacc[n] = __builtin_amdgcn_mfma_f32_16x16x32_bf16(pf, vf, oacc[n], 0, 0, 0);
            }
        }
        __syncthreads();
    }

    #pragma unroll
    for (int jj = 0; jj < 4; ++jj) {
        int q = q0 + wave * 16 + fgrp * 4 + jj;
        size_t ridx = (size_t)chunk * prows + ((size_t)b * LQ + q) * H + h;
        if (frow == 0) lsums[ridx] = lsum[jj];
        #pragma unroll
        for (int n = 0; n < 4; ++n)
            Opart[ridx * 64 + n * 16 + frow] = (__bf16)oacc[n][jj];
    }
}

// ---------------- deep_norm with NP partial-sum inputs + optional bias / A-copy ------
template<int NP, bool HASB, bool WRITE_BF>
__global__ __launch_bounds__(256) void deepnorm_k(const float* __restrict__ x,
                                                  const float* __restrict__ p0,
                                                  const float* __restrict__ p1,
                                                  const float* __restrict__ p2,
                                                  const float* __restrict__ p3,
                                                  const float* __restrict__ bias,
                                                  const float* __restrict__ g,
                                                  const float* __restrict__ b,
                                                  float* __restrict__ out,
                                                  __bf16* __restrict__ out_bf,
                                                  const float* __restrict__ Ain,
                                                  float* __restrict__ Aout) {
    int row = blockIdx.x;
    int tid = threadIdx.x;
    if (Aout && row == 0 && tid == 0) Aout[0] = Ain[0];
    size_t i0 = (size_t)row * 512 + tid, i1 = i0 + 256;
    float a0 = p0[i0], a1 = p0[i1];
    if (NP > 1) { a0 += p1[i0]; a1 += p1[i1]; }
    if (NP > 2) { a0 += p2[i0]; a1 += p2[i1]; }
    if (NP > 3) { a0 += p3[i0]; a1 += p3[i1]; }
    if (HASB)   { a0 += bias[tid]; a1 += bias[tid + 256]; }
    float v0 = x[i0] * 2.0f + a0;
    float v1 = x[i1] * 2.0f + a1;

    __shared__ float red[4];
    int wave = tid >> 6, lane = tid & 63;

    float s = v0 + v1;
    #pragma unroll
    for (int o = 32; o >= 1; o >>= 1) s += __shfl_xor(s, o);
    if (lane == 0) red[wave] = s;
    __syncthreads();
    float mean = (red[0] + red[1] + red[2] + red[3]) * (1.0f / 512.0f);

    float d0 = v0 - mean, d1 = v1 - mean;
    float vs = d0 * d0 + d1 * d1;
    #pragma unroll
    for (int o = 32; o >= 1; o >>= 1) vs += __shfl_xor(vs, o);
    __syncthreads();
    if (lane == 0) red[wave] = vs;
    __syncthreads();
    float var = (red[0] + red[1] + red[2] + red[3]) * (1.0f / 512.0f);
    float inv = rsqrtf(var + EPS);

    float o0 = d0 * inv * g[tid] + b[tid];
    float o1 = d1 * inv * g[tid + 256] + b[tid + 256];
    out[i0] = o0;
    out[i1] = o1;
    if (WRITE_BF) {
        out_bf[i0] = (__bf16)o0;
        out_bf[i1] = (__bf16)o1;
    }
}

// ---------------- launch ----------------
extern "C" void kernel_launch(void* const* d_in, const int* in_sizes, int n_in,
                              void* d_out, int out_size, void* d_ws, size_t ws_size,
                              hipStream_t stream) {
    const float* tgt  = (const float*)d_in[0];
    const float* mem  = (const float*)d_in[1];
    const float* dis_k1 = (const float*)d_in[2];
    const float* dis_q1 = (const float*)d_in[3];
    const float* dis_q2 = (const float*)d_in[4];
    const float* dis_k2 = (const float*)d_in[5];
    const float* A_in   = (const float*)d_in[10];
    const float* wq1 = (const float*)d_in[11]; const float* bq1 = (const float*)d_in[12];
    const float* wk1 = (const float*)d_in[13]; const float* bk1 = (const float*)d_in[14];
    const float* wv1 = (const float*)d_in[15]; const float* bv1 = (const float*)d_in[16];
    const float* wo1 = (const float*)d_in[17]; const float* bo1 = (const float*)d_in[18];
    const float* ln1g = (const float*)d_in[19]; const float* ln1b = (const float*)d_in[20];
    const float* wq2 = (const float*)d_in[21]; const float* bq2 = (const float*)d_in[22];
    const float* wk2 = (const float*)d_in[23]; const float* bk2 = (const float*)d_in[24];
    const float* wv2 = (const float*)d_in[25]; const float* bv2 = (const float*)d_in[26];
    const float* wo2 = (const float*)d_in[27]; const float* bo2 = (const float*)d_in[28];
    const float* ln2g = (const float*)d_in[29]; const float* ln2b = (const float*)d_in[30];
    const float* wff1 = (const float*)d_in[31]; const float* wff2 = (const float*)d_in[32];
    const float* ln3g = (const float*)d_in[33]; const float* ln3b = (const float*)d_in[34];

    char* ws = (char*)d_ws;
    auto MB = [&](size_t mb) { return ws + mb * 1024 * 1024; };

    __bf16* wqkv1_bf = (__bf16*)MB(0);     // 1.5MB
    __bf16* wo1_bf   = (__bf16*)MB(2);     // 0.5MB
    __bf16* wq2_bf   = (__bf16*)MB(3);     // 1MB
    __bf16* wkv2_bf  = (__bf16*)MB(4);     // 2MB
    __bf16* wo2_bf   = (__bf16*)MB(6);     // 1MB
    __bf16* wff1_bf  = (__bf16*)MB(7);     // 2MB
    __bf16* wff2_bf  = (__bf16*)MB(9);     // 2MB
    __bf16* tgt_bf   = (__bf16*)MB(11);    // 2MB, reused as x1_bf after qkv1+kv2
    __bf16* mem_bf   = (__bf16*)MB(13);    // 4MB
    __bf16* qkv1_bf  = (__bf16*)MB(17);    // 6MB, reused as q2_bf after attn1
    __bf16* Opart    = (__bf16*)MB(23);    // 8MB (23..31); reused as ffh_bf (8MB)
    float*  x1       = (float*)MB(31);     // 4MB (31..35)
    float*  post0    = (float*)MB(35);     // 4MB (35..39)
    float*  post1    = (float*)MB(39);     // 4MB (39..43)
    __bf16* kv2_bf   = (__bf16*)MB(43);    // 16MB (43..59) -- own region (written early)
    float*  x2       = (float*)MB(59);     // 4MB (59..63)
    __bf16* x2_bf    = (__bf16*)MB(63);    // 2MB (63..65)
    float*  lsums    = (float*)MB(65);     // 0.25MB
    __bf16* x1_bf    = tgt_bf;
    __bf16* q2_bf    = qkv1_bf;
    __bf16* ffh_bf   = Opart;

    float* out = (float*)d_out;

    // ---- conversions ----
    CvtJobs J;
    const float* srcs[12] = {tgt, mem, wq1, wk1, wv1, wo1, wq2, wk2, wv2, wo2, wff1, wff2};
    __bf16* dsts[12] = {tgt_bf, mem_bf, wqkv1_bf, wqkv1_bf + 262144, wqkv1_bf + 524288,
                        wo1_bf, wq2_bf, wkv2_bf, wkv2_bf + 524288, wo2_bf, wff1_bf, wff2_bf};
    int sizes[12] = {2048 * 512, 4096 * 512, 512 * 512, 512 * 512, 512 * 512, 512 * 512,
                     1024 * 512, 1024 * 512, 1024 * 512, 1024 * 512, 2048 * 512, 512 * 2048};
    int acc = 0;
    for (int i = 0; i < 12; ++i) { J.src[i] = srcs[i]; J.dst[i] = dsts[i]; J.off[i] = acc; acc += sizes[i] / 8; }
    J.off[12] = acc;
    cvt_k<<<(acc + 255) / 256, 256, 0, stream>>>(J, acc);

    // ---- merged qkv1 + kv2 (both depend only on cvt), 64x64 tiles ----
    GemmP p0, p1;
    p0.A = tgt_bf;  p0.W = wqkv1_bf; p0.b0 = bq1; p0.b1 = bk1; p0.b2 = bv1;
    p0.disK = dis_k1; p0.C = qkv1_bf;
    p0.bshift = 9; p0.ropeLo = 512; p0.ropeHi = 1024; p0.dstride = 512;
    p0.M = 2048; p0.N = 1536; p0.K = 512; p0.gx = 24; p0.nb = 768;
    p1.A = mem_bf;  p1.W = wkv2_bf;  p1.b0 = bk2; p1.b1 = bv2; p1.b2 = bv2;
    p1.disK = dis_k2; p1.C = kv2_bf;
    p1.bshift = 10; p1.ropeLo = 0; p1.ropeHi = 1024; p1.dstride = 1024;
    p1.M = 4096; p1.N = 2048; p1.K = 512; p1.gx = 32; p1.nb = 2048;
    gemm_dual_k<64><<<768 + 2048, 256, 0, stream>>>(p0, p1, 768);

    // ---- Phase 1: self-attention ----
    attn_bf16_k<true, 2><<<512, 256, 0, stream>>>(qkv1_bf, qkv1_bf + 512, qkv1_bf + 1024,
                                                  dis_q1, Opart, lsums,
                                                  8, 512, 512, 1536, 1536, 16384);
    gemm_wo_k<2><<<dim3(8, 32, 2), 256, 0, stream>>>(Opart, lsums, 16384, 8,
                                                     wo1_bf, post0, 2048, 512, 512);
    deepnorm_k<2, true, true><<<2048, 256, 0, stream>>>(tgt, post0, post1, nullptr, nullptr,
                                                        bo1, ln1g, ln1b, x1, x1_bf,
                                                        nullptr, nullptr);

    // ---- Phase 2: cross-attention ----
    gemm_bf16_k<64, 1, __bf16, false, true, false><<<dim3(16, 32), 256, 0, stream>>>(
        x1_bf, wq2_bf, bq2, bq2, bq2, 31, nullptr, 0, 0, 0,
        q2_bf, 2048, 1024, 512);
    attn_bf16_k<false, 2><<<1024, 256, 0, stream>>>(q2_bf, kv2_bf, kv2_bf + 1024,
                                                    dis_q2, Opart, lsums,
                                                    16, 512, 1024, 1024, 2048, 32768);
    gemm_wo_k<2><<<dim3(8, 32, 2), 256, 0, stream>>>(Opart, lsums, 32768, 16,
                                                     wo2_bf, post0, 2048, 512, 1024);
    deepnorm_k<2, true, true><<<2048, 256, 0, stream>>>(x1, post0, post1, nullptr, nullptr,
                                                        bo2, ln2g, ln2b, x2, x2_bf,
                                                        nullptr, nullptr);

    // ---- Phase 3: FFN ----
    gemm_bf16_k<64, 1, __bf16, true, false, false><<<dim3(32, 32), 256, 0, stream>>>(
        x2_bf, wff1_bf, nullptr, nullptr, nullptr, 31, nullptr, 0, 0, 0,
        ffh_bf, 2048, 2048, 512);
    gemm_bf16_k<64, 2, float, false, false, false><<<dim3(8, 32, 2), 256, 0, stream>>>(
        ffh_bf, wff2_bf, nullptr, nullptr, nullptr, 31, nullptr, 0, 0, 0,
        post0, 2048, 512, 2048);
    deepnorm_k<2, false, false><<<2048, 256, 0, stream>>>(x2, post0, post1, nullptr, nullptr,
                                                          nullptr, ln3g, ln3b, out, nullptr,
                                                          A_in, out + 2048 * 512);
}